// Round 1
// baseline (374.029 us; speedup 1.0000x reference)
//
#include <hip/hip_runtime.h>
#include <math.h>

#define BB 8
#define LL 64
#define NP 63          // frame pairs per batch
#define MM 16          // sampled frames
#define HH 112
#define WW 112
#define HW (HH*WW)
#define CIN 3
#define CMID 8
#define COUT 3
#define TAPS 49        // 7x7
#define PADK 3
#define TH 16          // stripe rows
#define TSTRIDE 120    // WW + 8 (pad for aligned float4)

// workspace byte offsets
#define WS_SCORES   0        // double[504]
#define WS_IDX      4096     // int[128]
#define WS_WT       4608     // float[1176]  conv_w transposed [c*49+k][o=8]
#define WS_WC       9344     // float[588]   combined weights  [c*49+k][o pad4]
#define WS_BIAS2    11712    // float[4]
#define WS_PART     11776    // float[128*6]
#define WS_STATS    14848    // float[6]

#define PD_EPS 1e-6f
#define BN_EPS 1e-5f

// ---------------------------------------------------------------- prep
__global__ void prep_kernel(const float* __restrict__ conv_w,
                            const float* __restrict__ conv_b,
                            const float* __restrict__ bneck_w,
                            char* __restrict__ ws)
{
    float* wT    = (float*)(ws + WS_WT);
    float* wc    = (float*)(ws + WS_WC);
    float* bias2 = (float*)(ws + WS_BIAS2);
    int tid = threadIdx.x;
    // transpose conv_w [o][c][k] -> [c*49+k][o]
    for (int i = tid; i < CMID*CIN*TAPS; i += blockDim.x) {
        int o  = i / (CIN*TAPS);
        int ck = i % (CIN*TAPS);
        wT[ck*CMID + o] = conv_w[i];
    }
    // combined 7x7 weights for the 1x1(8->3) o 7x7(3->8) composition
    for (int i = tid; i < CIN*TAPS; i += blockDim.x) {
        for (int o = 0; o < COUT; ++o) {
            float s = 0.f;
            for (int m = 0; m < CMID; ++m)
                s += bneck_w[o*CMID + m] * conv_w[m*CIN*TAPS + i];
            wc[i*4 + o] = s;
        }
        wc[i*4 + 3] = 0.f;
    }
    if (tid < COUT) {
        float s = 0.f;
        for (int m = 0; m < CMID; ++m) s += bneck_w[tid*CMID + m] * conv_b[m];
        bias2[tid] = s;
    }
}

// ---------------------------------------------------------------- scores
// one block per frame pair: conv7x7 on (x[t]-x[t+1]), per-pixel channel-L2,
// sum over pixels -> scores[pair]
__global__ __launch_bounds__(512) void score_kernel(
    const float* __restrict__ x, char* __restrict__ ws)
{
    __shared__ float wsh[CIN*TAPS*CMID];                    // 4704 B
    __shared__ __align__(16) float tile[CIN][TH+6][TSTRIDE];// 31680 B
    __shared__ double sred[8];

    const float* wT = (const float*)(ws + WS_WT);
    double* scores  = (double*)(ws + WS_SCORES);

    int pair = blockIdx.x;           // 0..503
    int b = pair / NP, t = pair % NP;
    const float* x0 = x + (size_t)(b*LL + t) * (CIN*HW);
    const float* x1 = x0 + CIN*HW;

    int tid = threadIdx.x;
    for (int i = tid; i < CIN*TAPS*CMID; i += 512) wsh[i] = wT[i];

    int iy = tid / 28;               // 448 active compute threads
    int xb = (tid % 28) * 4;
    bool active = tid < 448;

    double dacc = 0.0;

    for (int s = 0; s < HH/TH; ++s) {
        __syncthreads();
        int base = s*TH - PADK;
        for (int i = tid; i < CIN*(TH+6)*TSTRIDE; i += 512) {
            int c  = i / ((TH+6)*TSTRIDE);
            int r  = (i / TSTRIDE) % (TH+6);
            int cc = i % TSTRIDE;
            int gr = base + r, gc = cc - PADK;
            float v = 0.f;
            if (gr >= 0 && gr < HH && gc >= 0 && gc < WW) {
                int off = c*HW + gr*WW + gc;
                v = x0[off] - x1[off];
            }
            tile[c][r][cc] = v;
        }
        __syncthreads();
        if (active) {
            float acc[4][8];
            #pragma unroll
            for (int p = 0; p < 4; ++p)
                #pragma unroll
                for (int o = 0; o < 8; ++o) acc[p][o] = 0.f;
            for (int c = 0; c < 3; ++c) {
                for (int ky = 0; ky < 7; ++ky) {
                    const float* tr = &tile[c][iy+ky][xb];
                    float v[12];
                    *(float4*)&v[0] = *(const float4*)&tr[0];
                    *(float4*)&v[4] = *(const float4*)&tr[4];
                    *(float4*)&v[8] = *(const float4*)&tr[8];
                    #pragma unroll
                    for (int kx = 0; kx < 7; ++kx) {
                        const float4 w0 = *(const float4*)&wsh[(c*TAPS + ky*7 + kx)*8];
                        const float4 w1 = *(const float4*)&wsh[(c*TAPS + ky*7 + kx)*8 + 4];
                        #pragma unroll
                        for (int p = 0; p < 4; ++p) {
                            float vv = v[p + kx];
                            acc[p][0] += w0.x * vv;
                            acc[p][1] += w0.y * vv;
                            acc[p][2] += w0.z * vv;
                            acc[p][3] += w0.w * vv;
                            acc[p][4] += w1.x * vv;
                            acc[p][5] += w1.y * vv;
                            acc[p][6] += w1.z * vv;
                            acc[p][7] += w1.w * vv;
                        }
                    }
                }
            }
            #pragma unroll
            for (int p = 0; p < 4; ++p) {
                float ss = 0.f;
                #pragma unroll
                for (int o = 0; o < 8; ++o) {
                    float d = acc[p][o] + PD_EPS;
                    ss += d*d;
                }
                dacc += (double)sqrtf(ss);
            }
        }
    }
    // block reduction
    #pragma unroll
    for (int off = 32; off > 0; off >>= 1)
        dacc += __shfl_down(dacc, off, 64);
    int wid = tid >> 6, lane = tid & 63;
    if (lane == 0) sred[wid] = dacc;
    __syncthreads();
    if (tid == 0) {
        double s = 0.0;
        for (int wv = 0; wv < 8; ++wv) s += sred[wv];
        scores[pair] = s;
    }
}

// ---------------------------------------------------------------- sampling
__global__ void sample_kernel(char* __restrict__ ws)
{
    __shared__ double cum[BB][NP];
    const double* scores = (const double*)(ws + WS_SCORES);
    int* idxs = (int*)(ws + WS_IDX);
    int b = threadIdx.x;
    if (b < BB) {
        double tot = 0.0;
        for (int t = 0; t < NP; ++t) tot += sqrt(scores[b*NP + t]);
        double run = 0.0;
        for (int t = 0; t < NP; ++t) {
            run += sqrt(scores[b*NP + t]) / tot;   // frac then cumsum
            cum[b][t] = run;
        }
        for (int m = 0; m < MM; ++m) {
            float tf = (float)m / (float)(MM-1);
            double target = (double)tf;
            int best = 0;
            double bv = fabs(cum[b][0] - target);
            for (int t = 1; t < NP; ++t) {
                double v = fabs(cum[b][t] - target);
                if (v < bv) { bv = v; best = t; }   // strict: first min wins
            }
            idxs[b*MM + m] = best;
        }
    }
}

// ---------------------------------------------------------------- resblock conv
// one block per selected frame: combined 7x7 conv 3->3, write y into d_out,
// per-channel sum/sumsq partials for BN
__global__ __launch_bounds__(512) void resconv_kernel(
    const float* __restrict__ x, char* __restrict__ ws, float* __restrict__ out)
{
    __shared__ float wsh[CIN*TAPS*4];
    __shared__ __align__(16) float tile[CIN][TH+6][TSTRIDE];
    __shared__ double sred[8][6];

    const float* wc    = (const float*)(ws + WS_WC);
    const float* bias2 = (const float*)(ws + WS_BIAS2);
    const int* idxs    = (const int*)(ws + WS_IDX);
    float* part        = (float*)(ws + WS_PART);

    int n = blockIdx.x;          // 0..127
    int b = n / MM;
    int l = idxs[n];
    const float* src = x + (size_t)(b*LL + l) * (CIN*HW);
    float* ybase = out + (size_t)n * (COUT*HW);

    int tid = threadIdx.x;
    for (int i = tid; i < CIN*TAPS*4; i += 512) wsh[i] = wc[i];

    int iy = tid / 28;
    int xb = (tid % 28) * 4;
    bool active = tid < 448;

    double sum0=0, sum1=0, sum2=0, sq0=0, sq1=0, sq2=0;
    float bb0, bb1, bb2;
    bb0 = bias2[0]; bb1 = bias2[1]; bb2 = bias2[2];

    for (int s = 0; s < HH/TH; ++s) {
        __syncthreads();
        int base = s*TH - PADK;
        for (int i = tid; i < CIN*(TH+6)*TSTRIDE; i += 512) {
            int c  = i / ((TH+6)*TSTRIDE);
            int r  = (i / TSTRIDE) % (TH+6);
            int cc = i % TSTRIDE;
            int gr = base + r, gc = cc - PADK;
            float v = 0.f;
            if (gr >= 0 && gr < HH && gc >= 0 && gc < WW)
                v = src[c*HW + gr*WW + gc];
            tile[c][r][cc] = v;
        }
        __syncthreads();
        if (active) {
            float acc[4][3];
            #pragma unroll
            for (int p = 0; p < 4; ++p) {
                acc[p][0] = 0.f; acc[p][1] = 0.f; acc[p][2] = 0.f;
            }
            for (int c = 0; c < 3; ++c) {
                for (int ky = 0; ky < 7; ++ky) {
                    const float* tr = &tile[c][iy+ky][xb];
                    float v[12];
                    *(float4*)&v[0] = *(const float4*)&tr[0];
                    *(float4*)&v[4] = *(const float4*)&tr[4];
                    *(float4*)&v[8] = *(const float4*)&tr[8];
                    #pragma unroll
                    for (int kx = 0; kx < 7; ++kx) {
                        const float4 w0 = *(const float4*)&wsh[(c*TAPS + ky*7 + kx)*4];
                        #pragma unroll
                        for (int p = 0; p < 4; ++p) {
                            float vv = v[p + kx];
                            acc[p][0] += w0.x * vv;
                            acc[p][1] += w0.y * vv;
                            acc[p][2] += w0.z * vv;
                        }
                    }
                }
            }
            int gy = s*TH + iy;
            {
                float4 yv;
                float* pyv = (float*)&yv;
                #pragma unroll
                for (int p = 0; p < 4; ++p) {
                    float val = acc[p][0] + bb0;
                    pyv[p] = val; sum0 += val; sq0 += (double)val*val;
                }
                *(float4*)&ybase[0*HW + gy*WW + xb] = yv;
                #pragma unroll
                for (int p = 0; p < 4; ++p) {
                    float val = acc[p][1] + bb1;
                    pyv[p] = val; sum1 += val; sq1 += (double)val*val;
                }
                *(float4*)&ybase[1*HW + gy*WW + xb] = yv;
                #pragma unroll
                for (int p = 0; p < 4; ++p) {
                    float val = acc[p][2] + bb2;
                    pyv[p] = val; sum2 += val; sq2 += (double)val*val;
                }
                *(float4*)&ybase[2*HW + gy*WW + xb] = yv;
            }
        }
    }
    double vals[6] = {sum0, sum1, sum2, sq0, sq1, sq2};
    #pragma unroll
    for (int j = 0; j < 6; ++j) {
        #pragma unroll
        for (int off = 32; off > 0; off >>= 1)
            vals[j] += __shfl_down(vals[j], off, 64);
    }
    int wid = tid >> 6, lane = tid & 63;
    if (lane == 0) {
        #pragma unroll
        for (int j = 0; j < 6; ++j) sred[wid][j] = vals[j];
    }
    __syncthreads();
    if (tid < 6) {
        double s = 0.0;
        for (int wv = 0; wv < 8; ++wv) s += sred[wv][tid];
        part[n*6 + tid] = (float)s;
    }
}

// ---------------------------------------------------------------- stats reduce
__global__ void statreduce_kernel(char* __restrict__ ws)
{
    const float* part = (const float*)(ws + WS_PART);
    float* stats = (float*)(ws + WS_STATS);
    int j = threadIdx.x;
    if (j < 6) {
        double s = 0.0;
        for (int n = 0; n < BB*MM; ++n) s += part[n*6 + j];
        stats[j] = (float)s;
    }
}

// ---------------------------------------------------------------- finalize
// out = x_sel + relu(bn(y)), in-place over d_out (y already there)
__global__ __launch_bounds__(256) void finalize_kernel(
    const float* __restrict__ x, const float* __restrict__ gamma,
    const float* __restrict__ beta, const char* __restrict__ ws,
    float* __restrict__ out)
{
    const float* stats = (const float*)(ws + WS_STATS);
    const int* idxs    = (const int*)(ws + WS_IDX);
    int i4 = blockIdx.x * 256 + threadIdx.x;
    int i  = i4 * 4;
    int n  = i / (COUT*HW);
    int c  = (i / HW) % COUT;
    int hw = i % HW;
    int b  = n / MM;
    int l  = idxs[n];
    const float Ninv = 1.f / (float)(BB*MM*HW);
    float mean  = stats[c] * Ninv;
    float var   = stats[3+c] * Ninv - mean*mean;
    float scale = gamma[c] / sqrtf(var + BN_EPS);
    float shift = beta[c] - mean*scale;
    float4 y  = *(const float4*)&out[i];
    float4 xv = *(const float4*)&x[((size_t)(b*LL + l)*CIN + c)*HW + hw];
    float4 r;
    r.x = xv.x + fmaxf(y.x*scale + shift, 0.f);
    r.y = xv.y + fmaxf(y.y*scale + shift, 0.f);
    r.z = xv.z + fmaxf(y.z*scale + shift, 0.f);
    r.w = xv.w + fmaxf(y.w*scale + shift, 0.f);
    *(float4*)&out[i] = r;
}

// ---------------------------------------------------------------- launch
extern "C" void kernel_launch(void* const* d_in, const int* in_sizes, int n_in,
                              void* d_out, int out_size, void* d_ws, size_t ws_size,
                              hipStream_t stream)
{
    const float* x       = (const float*)d_in[0];
    const float* conv_w  = (const float*)d_in[1];
    const float* conv_b  = (const float*)d_in[2];
    const float* bneck_w = (const float*)d_in[3];
    const float* gamma   = (const float*)d_in[4];
    const float* beta    = (const float*)d_in[5];
    float* out = (float*)d_out;
    char* ws   = (char*)d_ws;

    prep_kernel<<<1, 256, 0, stream>>>(conv_w, conv_b, bneck_w, ws);
    score_kernel<<<BB*NP, 512, 0, stream>>>(x, ws);
    sample_kernel<<<1, 64, 0, stream>>>(ws);
    resconv_kernel<<<BB*MM, 512, 0, stream>>>(x, ws, out);
    statreduce_kernel<<<1, 64, 0, stream>>>(ws);
    int total4 = (BB*MM*COUT*HW) / 4;              // 1,204,224
    finalize_kernel<<<total4 / 256, 256, 0, stream>>>(x, gamma, beta, ws, out);
}

// Round 2
// 313.472 us; speedup vs baseline: 1.1932x; 1.1932x over previous
//
#include <hip/hip_runtime.h>
#include <math.h>

#define BB 8
#define LL 64
#define NP 63          // frame pairs per batch
#define MM 16          // sampled frames
#define HH 112
#define WW 112
#define HW (HH*WW)
#define CIN 3
#define CMID 8
#define COUT 3
#define TAPS 49        // 7x7
#define TH 16          // stripe rows
#define TSTRIDE 120    // WW + 8 (pad for aligned float4)
#define NTH 448        // 16 rows x 28 col-groups, 7 waves, all active
#define STAGE_ELEMS (CIN*(TH+6)*TSTRIDE)   // 7920

// workspace byte offsets
#define WS_SCORES   0        // double[504][2] = 8064 B
#define WS_IDX      8192     // int[128]
#define WS_WC       8704     // float[147*4] combined weights [k][o pad4]
#define WS_BIAS2    11072    // float[4]
#define WS_PART     11136    // float[256*6]
#define WS_STATS    17344    // float[6]

#define PD_EPS 1e-6f
#define BN_EPS 1e-5f

// ---------------------------------------------------------------- scores
// 2 blocks per frame pair (stripes 0-3 / 4-6): conv7x7 on (x[t]-x[t+1]),
// per-pixel channel-L2, partial sum -> scores[pair][half].
// Weights read from global with uniform indices -> s_load -> SGPR FMA operand.
__global__ __launch_bounds__(NTH) void score_kernel(
    const float* __restrict__ x, const float* __restrict__ wg,
    char* __restrict__ ws)
{
    __shared__ __align__(16) float tile[CIN][TH+6][TSTRIDE];
    __shared__ double sred[7];
    double* scores = (double*)(ws + WS_SCORES);

    int pair = blockIdx.x >> 1;
    int half = blockIdx.x & 1;
    int b = pair / NP, t = pair % NP;
    const float* x0 = x + (size_t)(b*LL + t) * (CIN*HW);
    const float* x1 = x0 + CIN*HW;

    int tid = threadIdx.x;
    int iy = tid / 28;
    int xb = (tid % 28) * 4;
    int s0 = half * 4, s1 = half ? 7 : 4;

    double dacc = 0.0;

    for (int s = s0; s < s1; ++s) {
        __syncthreads();
        int base = s*TH - 3;
        for (int i = tid; i < STAGE_ELEMS; i += NTH) {
            int c  = i / ((TH+6)*TSTRIDE);
            int r  = (i / TSTRIDE) % (TH+6);
            int cc = i % TSTRIDE;
            int gr = base + r, gc = cc - 3;
            float v = 0.f;
            if (gr >= 0 && gr < HH && gc >= 0 && gc < WW) {
                int off = c*HW + gr*WW + gc;
                v = x0[off] - x1[off];
            }
            tile[c][r][cc] = v;
        }
        __syncthreads();

        float acc[4][8];
        #pragma unroll
        for (int p = 0; p < 4; ++p)
            #pragma unroll
            for (int o = 0; o < 8; ++o) acc[p][o] = 0.f;

        #pragma unroll 1
        for (int cky = 0; cky < 21; ++cky) {
            int c = cky / 7, ky = cky % 7;
            const float* tr = &tile[c][iy + ky][xb];
            float v[12];
            *(float4*)&v[0] = *(const float4*)&tr[0];
            *(float4*)&v[4] = *(const float4*)&tr[4];
            *(float4*)&v[8] = *(const float4*)&tr[8];
            const float* wrow = wg + c*TAPS + ky*7;   // uniform base
            #pragma unroll
            for (int kx = 0; kx < 7; ++kx) {
                #pragma unroll
                for (int o = 0; o < 8; ++o) {
                    float wv = wrow[o*(CIN*TAPS) + kx];   // uniform -> SGPR
                    #pragma unroll
                    for (int p = 0; p < 4; ++p)
                        acc[p][o] += wv * v[p + kx];
                }
            }
        }

        #pragma unroll
        for (int p = 0; p < 4; ++p) {
            float ss = 0.f;
            #pragma unroll
            for (int o = 0; o < 8; ++o) {
                float d = acc[p][o] + PD_EPS;
                ss += d*d;
            }
            dacc += (double)sqrtf(ss);
        }
    }

    #pragma unroll
    for (int off = 32; off > 0; off >>= 1)
        dacc += __shfl_down(dacc, off, 64);
    int wid = tid >> 6, lane = tid & 63;
    if (lane == 0) sred[wid] = dacc;
    __syncthreads();
    if (tid == 0) {
        double ssum = 0.0;
        for (int w = 0; w < 7; ++w) ssum += sred[w];
        scores[pair*2 + half] = ssum;
    }
}

// ---------------------------------------------------------------- sample + prep
// single tiny block: (a) combined-weight prep for resblock, (b) cumsum + argmin
__global__ void sample_prep_kernel(const float* __restrict__ conv_w,
                                   const float* __restrict__ conv_b,
                                   const float* __restrict__ bneck_w,
                                   char* __restrict__ ws)
{
    __shared__ double cum[BB][NP];
    int tid = threadIdx.x;                 // 192 threads
    float* wcp   = (float*)(ws + WS_WC);
    float* bias2 = (float*)(ws + WS_BIAS2);

    // combined 7x7 weights for 1x1(8->3) o 7x7(3->8)
    for (int i = tid; i < CIN*TAPS; i += 192) {
        #pragma unroll
        for (int o = 0; o < COUT; ++o) {
            float s = 0.f;
            #pragma unroll
            for (int m = 0; m < CMID; ++m)
                s += bneck_w[o*CMID + m] * conv_w[m*CIN*TAPS + i];
            wcp[i*4 + o] = s;
        }
        wcp[i*4 + 3] = 0.f;
    }
    if (tid < COUT) {
        float s = 0.f;
        #pragma unroll
        for (int m = 0; m < CMID; ++m) s += bneck_w[tid*CMID + m] * conv_b[m];
        bias2[tid] = s;
    }

    // sampling
    const double* scores = (const double*)(ws + WS_SCORES);
    int* idxs = (int*)(ws + WS_IDX);
    if (tid < BB) {
        double tot = 0.0;
        for (int t = 0; t < NP; ++t)
            tot += sqrt(scores[(tid*NP + t)*2] + scores[(tid*NP + t)*2 + 1]);
        double run = 0.0;
        for (int t = 0; t < NP; ++t) {
            run += sqrt(scores[(tid*NP + t)*2] + scores[(tid*NP + t)*2 + 1]) / tot;
            cum[tid][t] = run;
        }
    }
    __syncthreads();
    if (tid < BB*MM) {
        int b = tid / MM, m = tid % MM;
        double target = (double)((float)m / 15.f);
        int best = 0;
        double bv = fabs(cum[b][0] - target);
        for (int t = 1; t < NP; ++t) {
            double v = fabs(cum[b][t] - target);
            if (v < bv) { bv = v; best = t; }   // strict: first min wins
        }
        idxs[tid] = best;
    }
}

// ---------------------------------------------------------------- resblock conv
// 2 blocks per selected frame: combined 7x7 conv 3->3, y -> d_out,
// per-channel sum/sumsq partials for BN. SGPR weights from ws.
__global__ __launch_bounds__(NTH) void resconv_kernel(
    const float* __restrict__ x, char* __restrict__ ws, float* __restrict__ out)
{
    __shared__ __align__(16) float tile[CIN][TH+6][TSTRIDE];
    __shared__ double sred[7][6];

    const float* wc    = (const float*)(ws + WS_WC);
    const float* bias2 = (const float*)(ws + WS_BIAS2);
    const int* idxs    = (const int*)(ws + WS_IDX);
    float* part        = (float*)(ws + WS_PART);

    int n = blockIdx.x >> 1;       // frame 0..127
    int half = blockIdx.x & 1;
    int b = n / MM;
    int l = idxs[n];
    const float* src = x + (size_t)(b*LL + l) * (CIN*HW);
    float* ybase = out + (size_t)n * (COUT*HW);

    int tid = threadIdx.x;
    int iy = tid / 28;
    int xb = (tid % 28) * 4;
    int s0 = half * 4, s1 = half ? 7 : 4;

    float bb0 = bias2[0], bb1 = bias2[1], bb2 = bias2[2];
    double sum0=0, sum1=0, sum2=0, sq0=0, sq1=0, sq2=0;

    for (int s = s0; s < s1; ++s) {
        __syncthreads();
        int base = s*TH - 3;
        for (int i = tid; i < STAGE_ELEMS; i += NTH) {
            int c  = i / ((TH+6)*TSTRIDE);
            int r  = (i / TSTRIDE) % (TH+6);
            int cc = i % TSTRIDE;
            int gr = base + r, gc = cc - 3;
            float v = 0.f;
            if (gr >= 0 && gr < HH && gc >= 0 && gc < WW)
                v = src[c*HW + gr*WW + gc];
            tile[c][r][cc] = v;
        }
        __syncthreads();

        float acc[4][3];
        #pragma unroll
        for (int p = 0; p < 4; ++p) { acc[p][0]=0.f; acc[p][1]=0.f; acc[p][2]=0.f; }

        #pragma unroll 1
        for (int cky = 0; cky < 21; ++cky) {
            int c = cky / 7, ky = cky % 7;
            const float* tr = &tile[c][iy + ky][xb];
            float v[12];
            *(float4*)&v[0] = *(const float4*)&tr[0];
            *(float4*)&v[4] = *(const float4*)&tr[4];
            *(float4*)&v[8] = *(const float4*)&tr[8];
            const float* wrow = wc + cky*28;          // uniform base
            #pragma unroll
            for (int kx = 0; kx < 7; ++kx) {
                #pragma unroll
                for (int o = 0; o < 3; ++o) {
                    float wv = wrow[kx*4 + o];        // uniform -> SGPR
                    #pragma unroll
                    for (int p = 0; p < 4; ++p)
                        acc[p][o] += wv * v[p + kx];
                }
            }
        }

        int gy = s*TH + iy;
        float4 yv; float* pyv = (float*)&yv;
        #pragma unroll
        for (int p = 0; p < 4; ++p) {
            float val = acc[p][0] + bb0;
            pyv[p] = val; sum0 += val; sq0 += (double)val*val;
        }
        *(float4*)&ybase[0*HW + gy*WW + xb] = yv;
        #pragma unroll
        for (int p = 0; p < 4; ++p) {
            float val = acc[p][1] + bb1;
            pyv[p] = val; sum1 += val; sq1 += (double)val*val;
        }
        *(float4*)&ybase[1*HW + gy*WW + xb] = yv;
        #pragma unroll
        for (int p = 0; p < 4; ++p) {
            float val = acc[p][2] + bb2;
            pyv[p] = val; sum2 += val; sq2 += (double)val*val;
        }
        *(float4*)&ybase[2*HW + gy*WW + xb] = yv;
    }

    double vals[6] = {sum0, sum1, sum2, sq0, sq1, sq2};
    #pragma unroll
    for (int j = 0; j < 6; ++j) {
        #pragma unroll
        for (int off = 32; off > 0; off >>= 1)
            vals[j] += __shfl_down(vals[j], off, 64);
    }
    int wid = tid >> 6, lane = tid & 63;
    if (lane == 0) {
        #pragma unroll
        for (int j = 0; j < 6; ++j) sred[wid][j] = vals[j];
    }
    __syncthreads();
    if (tid < 6) {
        double s = 0.0;
        for (int w = 0; w < 7; ++w) s += sred[w][tid];
        part[blockIdx.x*6 + tid] = (float)s;
    }
}

// ---------------------------------------------------------------- stats reduce
__global__ void statreduce_kernel(char* __restrict__ ws)
{
    const float* part = (const float*)(ws + WS_PART);
    float* stats = (float*)(ws + WS_STATS);
    int tid = threadIdx.x;            // 384 threads: 6 columns x 64 lanes
    int j = tid >> 6, lane = tid & 63;
    double s = 0.0;
    for (int n = lane; n < 2*BB*MM; n += 64) s += (double)part[n*6 + j];
    #pragma unroll
    for (int off = 32; off > 0; off >>= 1)
        s += __shfl_down(s, off, 64);
    if (lane == 0) stats[j] = (float)s;
}

// ---------------------------------------------------------------- finalize
// out = x_sel + relu(bn(y)), in-place over d_out (y already there)
__global__ __launch_bounds__(256) void finalize_kernel(
    const float* __restrict__ x, const float* __restrict__ gamma,
    const float* __restrict__ beta, const char* __restrict__ ws,
    float* __restrict__ out)
{
    const float* stats = (const float*)(ws + WS_STATS);
    const int* idxs    = (const int*)(ws + WS_IDX);
    int i4 = blockIdx.x * 256 + threadIdx.x;
    int i  = i4 * 4;
    int n  = i / (COUT*HW);
    int c  = (i / HW) % COUT;
    int hw = i % HW;
    int b  = n / MM;
    int l  = idxs[n];
    const float Ninv = 1.f / (float)(BB*MM*HW);
    float mean  = stats[c] * Ninv;
    float var   = stats[3+c] * Ninv - mean*mean;
    float scale = gamma[c] / sqrtf(var + BN_EPS);
    float shift = beta[c] - mean*scale;
    float4 y  = *(const float4*)&out[i];
    float4 xv = *(const float4*)&x[((size_t)(b*LL + l)*CIN + c)*HW + hw];
    float4 r;
    r.x = xv.x + fmaxf(y.x*scale + shift, 0.f);
    r.y = xv.y + fmaxf(y.y*scale + shift, 0.f);
    r.z = xv.z + fmaxf(y.z*scale + shift, 0.f);
    r.w = xv.w + fmaxf(y.w*scale + shift, 0.f);
    *(float4*)&out[i] = r;
}

// ---------------------------------------------------------------- launch
extern "C" void kernel_launch(void* const* d_in, const int* in_sizes, int n_in,
                              void* d_out, int out_size, void* d_ws, size_t ws_size,
                              hipStream_t stream)
{
    const float* x       = (const float*)d_in[0];
    const float* conv_w  = (const float*)d_in[1];
    const float* conv_b  = (const float*)d_in[2];
    const float* bneck_w = (const float*)d_in[3];
    const float* gamma   = (const float*)d_in[4];
    const float* beta    = (const float*)d_in[5];
    float* out = (float*)d_out;
    char* ws   = (char*)d_ws;

    score_kernel<<<BB*NP*2, NTH, 0, stream>>>(x, conv_w, ws);
    sample_prep_kernel<<<1, 192, 0, stream>>>(conv_w, conv_b, bneck_w, ws);
    resconv_kernel<<<BB*MM*2, NTH, 0, stream>>>(x, ws, out);
    statreduce_kernel<<<1, 384, 0, stream>>>(ws);
    int total4 = (BB*MM*COUT*HW) / 4;
    finalize_kernel<<<total4 / 256, 256, 0, stream>>>(x, gamma, beta, ws, out);
}